// Round 16
// baseline (80.468 us; speedup 1.0000x reference)
//
#include <hip/hip_runtime.h>
#include <hip/hip_bf16.h>

// ---------- types ----------
typedef short bf16x8 __attribute__((ext_vector_type(8)));   // 8 bf16 = 4 VGPR
typedef float f32x4 __attribute__((ext_vector_type(4)));
typedef unsigned short ushort_t;

#define SQ 2048
#define DIM 1024
#define NH 16
#define HD 64

__device__ __forceinline__ ushort_t f2bf(float f) {
    __hip_bfloat16 h = __float2bfloat16(f);     // HW v_cvt, RNE
    return *reinterpret_cast<ushort_t*>(&h);
}

__device__ __forceinline__ void load_lds16(const void* g, void* l) {
    __builtin_amdgcn_global_load_lds(
        (const __attribute__((address_space(1))) unsigned int*)g,
        (__attribute__((address_space(3))) unsigned int*)l, 16, 0, 0);
}

// ---------- fused prep: cvt_x | transpose(w_qkv) | transpose(w_out) ----------
__global__ void prep_kernel(const float* __restrict__ x, ushort_t* __restrict__ xb,
                            const float* __restrict__ w_qkv, ushort_t* __restrict__ wqkvT,
                            const float* __restrict__ w_out, ushort_t* __restrict__ woutT) {
    __shared__ ushort_t tile[32][33];
    const int bid = blockIdx.x;
    const int tid = threadIdx.x;
    if (bid < 1024) {
        int i = bid * 256 + tid;
        const int stride = 1024 * 256;
        const int n4 = 4096 * 1024 / 4;
        for (; i < n4; i += stride) {
            float4 f = reinterpret_cast<const float4*>(x)[i];
            ushort4 o;
            o.x = f2bf(f.x); o.y = f2bf(f.y); o.z = f2bf(f.z); o.w = f2bf(f.w);
            reinterpret_cast<ushort4*>(xb)[i] = o;
        }
        return;
    }
    if (bid < 4096) {
        int idx = bid - 1024;
        int cx = idx % 96, ry = idx / 96;
        int c0 = cx * 32, r0 = ry * 32;
        int tx = tid & 31, ty = tid >> 5;
#pragma unroll
        for (int i = 0; i < 32; i += 8)
            tile[ty + i][tx] = f2bf(w_qkv[(size_t)(r0 + ty + i) * 3072 + c0 + tx]);
        __syncthreads();
#pragma unroll
        for (int i = 0; i < 32; i += 8)
            wqkvT[(size_t)(c0 + ty + i) * 1024 + r0 + tx] = tile[tx][ty + i];
        return;
    }
    {
        int idx = bid - 4096;
        int cx = idx % 32, ry = idx / 32;
        int c0 = cx * 32, r0 = ry * 32;
        int tx = tid & 31, ty = tid >> 5;
#pragma unroll
        for (int i = 0; i < 32; i += 8)
            tile[ty + i][tx] = f2bf(w_out[(size_t)(r0 + ty + i) * 1024 + c0 + tx]);
        __syncthreads();
#pragma unroll
        for (int i = 0; i < 32; i += 8)
            woutT[(size_t)(c0 + ty + i) * 1024 + r0 + tx] = tile[tx][ty + i];
    }
}

// ---------- kernel 2b: per-(b,h) V transpose ----------
__global__ void transpose_v(const ushort_t* __restrict__ qkv, ushort_t* __restrict__ vt) {
    __shared__ ushort_t tile[32][33];
    int s0 = blockIdx.x * 32, d0 = blockIdx.y * 32;
    int bh = blockIdx.z;                        // b*16+h
    int b = bh >> 4, h = bh & 15;
    const ushort_t* src = qkv + (size_t)(b * SQ) * 3072 + 2048 + h * 64;
    ushort_t* dst = vt + (size_t)bh * HD * SQ;
    int tx = threadIdx.x, ty = threadIdx.y;     // block (32,8)
#pragma unroll
    for (int i = 0; i < 32; i += 8)
        tile[ty + i][tx] = src[(size_t)(s0 + ty + i) * 3072 + d0 + tx];
    __syncthreads();
#pragma unroll
    for (int i = 0; i < 32; i += 8)
        dst[(size_t)(d0 + ty + i) * SQ + s0 + tx] = tile[tx][ty + i];
}

// =====================================================================
// GEMM1 (reverted to R11 best): 256x192 tile, 4-phase counted-vmcnt.
// =====================================================================

#define STAGE_U(Gptr, ldk, grow0, kcol, regionbase)                          \
  { int row_ = tid >> 3;                                                      \
    int sc_ = (tid & 7) ^ (row_ & 7);                                         \
    load_lds16((Gptr) + (size_t)((grow0) + row_) * (ldk) + (kcol) + sc_ * 8,  \
               (regionbase) + tid * 16); }

#define DS_A192(BASE, EXTRA)                                                  \
  _Pragma("unroll") for (int kk_ = 0; kk_ < 2; ++kk_)                         \
  _Pragma("unroll") for (int m_ = 0; m_ < 4; ++m_)                            \
    a[kk_][m_] = *reinterpret_cast<const bf16x8*>((BASE) + (EXTRA) + offA[kk_][m_]);

#define DS_B192(BASE)                                                         \
  _Pragma("unroll") for (int kk_ = 0; kk_ < 2; ++kk_)                         \
  _Pragma("unroll") for (int n_ = 0; n_ < 3; ++n_)                            \
    b[kk_][n_] = *reinterpret_cast<const bf16x8*>((BASE) + offB[kk_][n_]);

#define BAR_LGKM                                                              \
  __builtin_amdgcn_s_barrier();                                               \
  asm volatile("s_waitcnt lgkmcnt(0)" ::: "memory");                          \
  __builtin_amdgcn_sched_barrier(0);

#define MFMA_Q(MQ)                                                            \
  __builtin_amdgcn_s_setprio(1);                                              \
  _Pragma("unroll") for (int kk_ = 0; kk_ < 2; ++kk_)                         \
  _Pragma("unroll") for (int m_ = 0; m_ < 4; ++m_)                            \
  _Pragma("unroll") for (int n_ = 0; n_ < 3; ++n_)                            \
    acc[(MQ)*4 + m_][n_] = __builtin_amdgcn_mfma_f32_16x16x32_bf16(           \
        a[kk_][m_], b[kk_][n_], acc[(MQ)*4 + m_][n_], 0, 0, 0);               \
  __builtin_amdgcn_s_setprio(0);

__global__ __launch_bounds__(512, 2)
void gemm192_bt(const ushort_t* __restrict__ A, const ushort_t* __restrict__ Bt,
                const float* __restrict__ bias, ushort_t* __restrict__ Cout,
                int M, int N, int K, int nbn) {
    __shared__ char sm[114688];
    const int tid = threadIdx.x;
    const int lane = tid & 63;
    const int w = tid >> 6;                 // 0..7
    const int wm = w >> 2, wn = w & 3;      // 2M x 4N waves
    const int r = lane & 15, hi = lane >> 4;

    const int cpx = gridDim.x >> 3;
    const int bid = blockIdx.x;
    const int x = (bid & 7) * cpx + (bid >> 3);
    const int bm = x / nbn, bn = x % nbn;
    const int m0 = bm * 256, n0 = bn * 192;

    const int NT = K >> 6;                  // 16 K-tiles
    const int NI = NT >> 1;                 // 8 iterations

    char* const A0 = sm;
    char* const B0 = sm + 32768;
    char* const A1 = sm + 57344;
    char* const B1 = sm + 90112;

    int offA[2][4], offB[2][3];
#pragma unroll
    for (int kk = 0; kk < 2; ++kk) {
#pragma unroll
        for (int m = 0; m < 4; ++m) {
            int rowL = wm * 128 + m * 16 + r;
            offA[kk][m] = rowL * 128 + (((kk * 4 + hi) ^ (rowL & 7)) * 16);
        }
#pragma unroll
        for (int n = 0; n < 3; ++n) {
            int rowL = wn * 48 + n * 16 + r;
            offB[kk][n] = rowL * 128 + (((kk * 4 + hi) ^ (rowL & 7)) * 16);
        }
    }

    f32x4 acc[8][3];
#pragma unroll
    for (int am = 0; am < 8; ++am)
#pragma unroll
        for (int an = 0; an < 3; ++an) acc[am][an] = (f32x4){0.f, 0.f, 0.f, 0.f};

    bf16x8 a[2][4], b[2][3];

    STAGE_U(A,  K, m0,        0, A0);
    STAGE_U(A,  K, m0 + 64,   0, A0 + 8192);
    STAGE_U(A,  K, m0 + 128,  0, A0 + 16384);
    STAGE_U(A,  K, m0 + 192,  0, A0 + 24576);
    STAGE_U(Bt, K, n0,        0, B0);
    STAGE_U(Bt, K, n0 + 64,   0, B0 + 8192);
    STAGE_U(Bt, K, n0 + 128,  0, B0 + 16384);
    STAGE_U(A,  K, m0,       64, A1);
    STAGE_U(A,  K, m0 + 128, 64, A1 + 16384);
    asm volatile("s_waitcnt vmcnt(2)" ::: "memory");
    __builtin_amdgcn_s_barrier();

    for (int i = 0; i < NI; ++i) {
        const int k1 = (2 * i + 1) * 64;
        const int k2 = ((2 * i + 2) % NT) * 64;
        const int k3 = ((2 * i + 3) % NT) * 64;

        STAGE_U(A,  K, m0 + 64,  k1, A1 + 8192);
        STAGE_U(A,  K, m0 + 192, k1, A1 + 24576);
        STAGE_U(Bt, K, n0,       k1, B1);
        STAGE_U(Bt, K, n0 + 64,  k1, B1 + 8192);
        STAGE_U(Bt, K, n0 + 128, k1, B1 + 16384);
        DS_A192(A0, 0); DS_B192(B0);
        BAR_LGKM; MFMA_Q(0);
        __builtin_amdgcn_s_barrier();

        STAGE_U(A, K, m0,       k2, A0);
        STAGE_U(A, K, m0 + 128, k2, A0 + 16384);
        DS_A192(A0, 8192);
        BAR_LGKM; MFMA_Q(1);
        asm volatile("s_waitcnt vmcnt(2)" ::: "memory");
        __builtin_amdgcn_s_barrier();

        STAGE_U(A,  K, m0 + 64,  k2, A0 + 8192);
        STAGE_U(A,  K, m0 + 192, k2, A0 + 24576);
        STAGE_U(Bt, K, n0,       k2, B0);
        STAGE_U(Bt, K, n0 + 64,  k2, B0 + 8192);
        STAGE_U(Bt, K, n0 + 128, k2, B0 + 16384);
        DS_A192(A1, 0); DS_B192(B1);
        BAR_LGKM; MFMA_Q(0);
        __builtin_amdgcn_s_barrier();

        STAGE_U(A, K, m0,       k3, A1);
        STAGE_U(A, K, m0 + 128, k3, A1 + 16384);
        DS_A192(A1, 8192);
        BAR_LGKM; MFMA_Q(1);
        asm volatile("s_waitcnt vmcnt(2)" ::: "memory");
        __builtin_amdgcn_s_barrier();
    }

#pragma unroll
    for (int am = 0; am < 8; ++am) {
        int rowg = m0 + wm * 128 + (am >> 2) * 64 + (am & 3) * 16 + hi * 4;
#pragma unroll
        for (int an = 0; an < 3; ++an) {
            int colg = n0 + wn * 48 + an * 16 + r;
            float bv = bias[colg];
#pragma unroll
            for (int j = 0; j < 4; ++j) {
                float v = acc[am][an][j] + bv;
                Cout[(size_t)(rowg + j) * N + colg] = f2bf(v);
            }
        }
    }
}

// =====================================================================
// GEMM2 v2: 128x128 tile, 256 threads, 4 waves (2x2) x 64x64 per wave.
// Halves per-FLOP LDS reads (16 reads / 32 MFMA per K-tile) and fits
// 64KB LDS -> 2 blocks/CU co-resident. Same 4-phase counted-vmcnt
// ledger (kk-split, B held in regs): prologue {T0.A,T0.B,T1.B}=12 inst,
// vmcnt(4); ph2/ph4 vmcnt(4).
// =====================================================================

#define STAGE_U2(Gptr, ldk, grow0, kcol, regionbase)                          \
  { _Pragma("unroll")                                                         \
    for (int j_ = 0; j_ < 2; ++j_) {                                          \
      int task_ = j_ * 256 + tid;                                             \
      int row_ = task_ >> 3;                                                  \
      int sc_ = (task_ & 7) ^ (row_ & 7);                                     \
      load_lds16((Gptr) + (size_t)((grow0) + row_) * (ldk) + (kcol) + sc_ * 8,\
                 (regionbase) + task_ * 16); } }

#define G2_A(BASE, KK)                                                        \
  _Pragma("unroll") for (int m_ = 0; m_ < 4; ++m_)                            \
    a2[m_] = *reinterpret_cast<const bf16x8*>((BASE) + offA2[KK][m_]);

#define G2_B(BASE)                                                            \
  _Pragma("unroll") for (int kk_ = 0; kk_ < 2; ++kk_)                         \
  _Pragma("unroll") for (int n_ = 0; n_ < 4; ++n_)                            \
    b2[kk_][n_] = *reinterpret_cast<const bf16x8*>((BASE) + offB2[kk_][n_]);

#define G2_MFMA(KK)                                                           \
  __builtin_amdgcn_s_setprio(1);                                              \
  _Pragma("unroll") for (int m_ = 0; m_ < 4; ++m_)                            \
  _Pragma("unroll") for (int n_ = 0; n_ < 4; ++n_)                            \
    acc[m_][n_] = __builtin_amdgcn_mfma_f32_16x16x32_bf16(                    \
        a2[m_], b2[KK][n_], acc[m_][n_], 0, 0, 0);                            \
  __builtin_amdgcn_s_setprio(0);

__global__ __launch_bounds__(256, 2)
void gemm128_v2(const ushort_t* __restrict__ A, const ushort_t* __restrict__ Bt,
                const float* __restrict__ bias, float* __restrict__ Cout,
                int M, int N, int K, int nbn) {
    __shared__ char sm[65536];
    const int tid = threadIdx.x;
    const int lane = tid & 63;
    const int w = tid >> 6;                 // 0..3
    const int wm = w >> 1, wn = w & 1;      // 2M x 2N waves, 64x64 each
    const int r = lane & 15, hi = lane >> 4;

    const int cpx = gridDim.x >> 3;
    const int bid = blockIdx.x;
    const int x = (bid & 7) * cpx + (bid >> 3);
    const int bm = x / nbn, bn = x % nbn;
    const int m0 = bm * 128, n0 = bn * 128;

    const int NT = K >> 6;                  // 16
    const int NI = NT >> 1;                 // 8

    char* const A0 = sm;                    // 16KB each
    char* const B0 = sm + 16384;
    char* const A1 = sm + 32768;
    char* const B1 = sm + 49152;

    int offA2[2][4], offB2[2][4];
#pragma unroll
    for (int kk = 0; kk < 2; ++kk) {
#pragma unroll
        for (int m = 0; m < 4; ++m) {
            int rowL = wm * 64 + m * 16 + r;
            offA2[kk][m] = rowL * 128 + (((kk * 4 + hi) ^ (rowL & 7)) * 16);
        }
#pragma unroll
        for (int n = 0; n < 4; ++n) {
            int rowL = wn * 64 + n * 16 + r;
            offB2[kk][n] = rowL * 128 + (((kk * 4 + hi) ^ (rowL & 7)) * 16);
        }
    }

    f32x4 acc[4][4];
#pragma unroll
    for (int m = 0; m < 4; ++m)
#pragma unroll
        for (int n = 0; n < 4; ++n) acc[m][n] = (f32x4){0.f, 0.f, 0.f, 0.f};

    bf16x8 a2[4], b2[2][4];

    // prologue: T0.A, T0.B, T1.B (12 inst); keep T1.B (4) in flight
    STAGE_U2(A,  K, m0,       0, A0);
    STAGE_U2(A,  K, m0 + 64,  0, A0 + 8192);
    STAGE_U2(Bt, K, n0,       0, B0);
    STAGE_U2(Bt, K, n0 + 64,  0, B0 + 8192);
    STAGE_U2(Bt, K, n0,      64, B1);
    STAGE_U2(Bt, K, n0 + 64, 64, B1 + 8192);
    asm volatile("s_waitcnt vmcnt(4)" ::: "memory");
    __builtin_amdgcn_s_barrier();

    for (int i = 0; i < NI; ++i) {
        const int k1 = (2 * i + 1) * 64;
        const int k2 = ((2 * i + 2) % NT) * 64;
        const int k3 = ((2 * i + 3) % NT) * 64;

        // ph1: stage T1.A; read A0 kk0 + B0 (both kk); MFMA kk0
        STAGE_U2(A, K, m0,      k1, A1);
        STAGE_U2(A, K, m0 + 64, k1, A1 + 8192);
        G2_A(A0, 0); G2_B(B0);
        BAR_LGKM; G2_MFMA(0);
        __builtin_amdgcn_s_barrier();

        // ph2: stage T2.B -> B0 (B0 regs held); read A0 kk1; MFMA kk1; vmcnt(4)
        STAGE_U2(Bt, K, n0,      k2, B0);
        STAGE_U2(Bt, K, n0 + 64, k2, B0 + 8192);
        G2_A(A0, 1);
        BAR_LGKM; G2_MFMA(1);
        asm volatile("s_waitcnt vmcnt(4)" ::: "memory");
        __builtin_amdgcn_s_barrier();

        // ph3: stage T2.A -> A0; read A1 kk0 + B1 (both kk); MFMA kk0
        STAGE_U2(A, K, m0,      k2, A0);
        STAGE_U2(A, K, m0 + 64, k2, A0 + 8192);
        G2_A(A1, 0); G2_B(B1);
        BAR_LGKM; G2_MFMA(0);
        __builtin_amdgcn_s_barrier();

        // ph4: stage T3.B -> B1; read A1 kk1; MFMA kk1; vmcnt(4)
        STAGE_U2(Bt, K, n0,      k3, B1);
        STAGE_U2(Bt, K, n0 + 64, k3, B1 + 8192);
        G2_A(A1, 1);
        BAR_LGKM; G2_MFMA(1);
        asm volatile("s_waitcnt vmcnt(4)" ::: "memory");
        __builtin_amdgcn_s_barrier();
    }

    // epilogue: f32 out + bias
#pragma unroll
    for (int m = 0; m < 4; ++m) {
        int rowg = m0 + wm * 64 + m * 16 + hi * 4;
#pragma unroll
        for (int n = 0; n < 4; ++n) {
            int colg = n0 + wn * 64 + n * 16 + r;
            float bv = bias[colg];
#pragma unroll
            for (int j = 0; j < 4; ++j)
                Cout[(size_t)(rowg + j) * N + colg] = acc[m][n][j] + bv;
        }
    }
}

// ---------- banded attention v4 (reverted to R11/R12 best): K staged,
// V direct-global, P aliases K; 25.6KB LDS -> 4 blocks/CU. ----------
__global__ __launch_bounds__(256, 4)
void attn_kernel(const ushort_t* __restrict__ qkv, const ushort_t* __restrict__ vt,
                 ushort_t* __restrict__ attn_out) {
    __shared__ char smem[25600];

    const int bid0 = blockIdx.x;
    const int bid = (bid0 & 7) * 128 + (bid0 >> 3);   // XCD-chunked
    const int qb = bid & 31;
    const int h = (bid >> 5) & 15;
    const int b = bid >> 9;
    const int q0 = qb * 64;
    const int kstart = (q0 - 64 > 0) ? (q0 - 64) : 0;

    const int tid = threadIdx.x;
    const int lane = tid & 63;
    const int w = tid >> 6;
    const int r = lane & 15, hi = lane >> 4;

    // ---- stage K [192][64] @0 (swizzled, zero-fill OOB) ----
#pragma unroll
    for (int i = 0; i < 6; ++i) {
        int task = i * 256 + tid;
        int row = task >> 3, ch = task & 7;
        int key = kstart + row;
        uint4 v = make_uint4(0u, 0u, 0u, 0u);
        if (key < SQ)
            v = *reinterpret_cast<const uint4*>(
                qkv + (size_t)(b * SQ + key) * 3072 + 1024 + h * 64 + ch * 8);
        int byte = row * 128 + ch * 16; byte ^= (row & 7) << 4;
        *reinterpret_cast<uint4*>(smem + byte) = v;
    }

    // ---- Q directly into A-fragments ----
    const ushort_t* qrow = qkv + (size_t)(b * SQ + q0 + w * 16 + r) * 3072 + h * 64;
    bf16x8 aq0 = *reinterpret_cast<const bf16x8*>(qrow + hi * 8);
    bf16x8 aq1 = *reinterpret_cast<const bf16x8*>(qrow + 32 + hi * 8);

    __syncthreads();   // barrier #1

    const int delta = q0 - kstart;
    const int base = w * 16 + delta;
    int tmin = (base - 64) >> 4; if (tmin < 0) tmin = 0;
    int tmax = (base + 79) >> 4;
    int tcap = (SQ - 1 - kstart) >> 4; if (tmax > tcap) tmax = tcap;
    if (tmax > 11) tmax = 11;
    const int ksmin = tmin >> 1, ksmax = tmax >> 1;

    f32x4 acc[12];
#pragma unroll
    for (int t = 0; t < 12; ++t) acc[t] = (f32x4){0.f, 0.f, 0.f, 0.f};
#pragma unroll
    for (int t = 0; t < 12; ++t) {
        if (t < tmin || t > tmax) continue;
#pragma unroll
        for (int ks = 0; ks < 2; ++ks) {
            int row = t * 16 + r;
            int byte = row * 128 + ks * 64 + hi * 16; byte ^= (row & 7) << 4;
            bf16x8 bk = *reinterpret_cast<const bf16x8*>(smem + byte);
            acc[t] = __builtin_amdgcn_mfma_f32_16x16x32_bf16(
                ks == 0 ? aq0 : aq1, bk, acc[t], 0, 0, 0);
        }
    }

    float mrow[4], lrow[4];
#pragma unroll
    for (int t = 0; t < 12; ++t) {
        if (t < tmin || t > tmax) continue;
        int key = kstart + t * 16 + r;
#pragma unroll
        for (int j = 0; j < 4; ++j) {
            int qrow_g = q0 + w * 16 + hi * 4 + j;
            int dd = key - qrow_g; if (dd < 0) dd = -dd;
            bool valid = (key < SQ) && (dd <= 64);
            acc[t][j] = valid ? acc[t][j] * 0.125f : -1e30f;
        }
    }
#pragma unroll
    for (int j = 0; j < 4; ++j) {
        float m = -1e30f;
#pragma unroll
        for (int t = 0; t < 12; ++t) {
            if (t < tmin || t > tmax) continue;
            m = fmaxf(m, acc[t][j]);
        }
        m = fmaxf(m, __shfl_xor(m, 1));
        m = fmaxf(m, __shfl_xor(m, 2));
        m = fmaxf(m, __shfl_xor(m, 4));
        m = fmaxf(m, __shfl_xor(m, 8));
        mrow[j] = m;
    }
#pragma unroll
    for (int j = 0; j < 4; ++j) {
        float s = 0.f;
#pragma unroll
        for (int t = 0; t < 12; ++t) {
            if (t < tmin || t > tmax) continue;
            float p = __expf(acc[t][j] - mrow[j]);
            acc[t][j] = p;
            s += p;
        }
        s += __shfl_xor(s, 1);
        s += __shfl_xor(s, 2);
        s += __shfl_xor(s, 4);
        s += __shfl_xor(s, 8);
        lrow[j] = s;
    }

    __syncthreads();   // barrier #2

#pragma unroll
    for (int t = 0; t < 12; ++t) {
        int col = t * 16 + r;
        bool inb = (t >= tmin) && (t <= tmax);
#pragma unroll
        for (int j = 0; j < 4; ++j) {
            int rowL = w * 16 + hi * 4 + j;
            ushort_t pv = inb ? f2bf(acc[t][j]) : (ushort_t)0;
            *reinterpret_cast<ushort_t*>(smem + rowL * 400 + col * 2) = pv;
        }
    }
    // same-wave write->read dependency: compiler inserts lgkmcnt; no barrier.

    const ushort_t* vtb = vt + (size_t)(b * NH + h) * HD * SQ;
    f32x4 oacc[4];
#pragma unroll
    for (int dt = 0; dt < 4; ++dt) oacc[dt] = (f32x4){0.f, 0.f, 0.f, 0.f};
#pragma unroll
    for (int ks = 0; ks < 6; ++ks) {
        if (ks < ksmin || ks > ksmax) continue;
        int k0 = ks * 32 + hi * 8;
        bf16x8 ap = *reinterpret_cast<const bf16x8*>(
            smem + (w * 16 + r) * 400 + k0 * 2);
        int k8 = kstart + k0;
        if (k8 > SQ - 8) k8 = SQ - 8;
#pragma unroll
        for (int dt = 0; dt < 4; ++dt) {
            int d = dt * 16 + r;
            bf16x8 bv = *reinterpret_cast<const bf16x8*>(vtb + (size_t)d * SQ + k8);
            oacc[dt] = __builtin_amdgcn_mfma_f32_16x16x32_bf16(ap, bv, oacc[dt], 0, 0, 0);
        }
    }

    float inv[4];
#pragma unroll
    for (int j = 0; j < 4; ++j) inv[j] = 1.0f / lrow[j];
#pragma unroll
    for (int dt = 0; dt < 4; ++dt) {
        int d = dt * 16 + r;
#pragma unroll
        for (int j = 0; j < 4; ++j) {
            int q = q0 + w * 16 + hi * 4 + j;
            attn_out[(size_t)(b * SQ + q) * 1024 + h * 64 + d] = f2bf(oacc[dt][j] * inv[j]);
        }
    }
}

// ---------- launch ----------
extern "C" void kernel_launch(void* const* d_in, const int* in_sizes, int n_in,
                              void* d_out, int out_size, void* d_ws, size_t ws_size,
                              hipStream_t stream) {
    const float* x     = (const float*)d_in[0];
    const float* w_qkv = (const float*)d_in[1];
    const float* b_qkv = (const float*)d_in[2];
    const float* w_out = (const float*)d_in[3];
    const float* b_out = (const float*)d_in[4];
    float* out = (float*)d_out;

    char* ws = (char*)d_ws;
    ushort_t* xb    = (ushort_t*)(ws);                       // 8 MB  [4096][1024]
    ushort_t* wqkvT = (ushort_t*)(ws + 8388608);             // 6 MB  [3072][1024]
    ushort_t* woutT = (ushort_t*)(ws + 14680064);            // 2 MB  [1024][1024]
    ushort_t* qkv   = (ushort_t*)(ws + 16777216);            // 24 MB [4096][3072]
    ushort_t* aout  = (ushort_t*)(ws + 41943040);            // 8 MB  [4096][1024]
    ushort_t* vtbuf = (ushort_t*)(ws + 50331648);            // 8 MB  [32][64][2048]

    prep_kernel<<<5120, 256, 0, stream>>>(x, xb, w_qkv, wqkvT, w_out, woutT);

    gemm192_bt<<<256, 512, 0, stream>>>(xb, wqkvT, b_qkv, qkv, 4096, 3072, 1024, 16);
    transpose_v<<<dim3(64, 2, 32), dim3(32, 8), 0, stream>>>(qkv, vtbuf);
    attn_kernel<<<1024, 256, 0, stream>>>(qkv, vtbuf, aout);
    // GEMM2 v2: 4096x1024x1024, 128x128 tiles -> 256 blocks of 256 thr, 2/CU
    gemm128_v2<<<256, 256, 0, stream>>>(aout, woutT, b_out, out, 4096, 1024, 1024, 8);
}

// Round 17
// 78.035 us; speedup vs baseline: 1.0312x; 1.0312x over previous
//
#include <hip/hip_runtime.h>
#include <hip/hip_bf16.h>

// ---------- types ----------
typedef short bf16x8 __attribute__((ext_vector_type(8)));   // 8 bf16 = 4 VGPR
typedef float f32x4 __attribute__((ext_vector_type(4)));
typedef unsigned short ushort_t;

#define SQ 2048
#define DIM 1024
#define NH 16
#define HD 64

__device__ __forceinline__ ushort_t f2bf(float f) {
    __hip_bfloat16 h = __float2bfloat16(f);     // HW v_cvt, RNE
    return *reinterpret_cast<ushort_t*>(&h);
}

__device__ __forceinline__ void load_lds16(const void* g, void* l) {
    __builtin_amdgcn_global_load_lds(
        (const __attribute__((address_space(1))) unsigned int*)g,
        (__attribute__((address_space(3))) unsigned int*)l, 16, 0, 0);
}

// ---------- fused prep: cvt_x | transpose(w_qkv) | transpose(w_out) ----------
__global__ void prep_kernel(const float* __restrict__ x, ushort_t* __restrict__ xb,
                            const float* __restrict__ w_qkv, ushort_t* __restrict__ wqkvT,
                            const float* __restrict__ w_out, ushort_t* __restrict__ woutT) {
    __shared__ ushort_t tile[32][33];
    const int bid = blockIdx.x;
    const int tid = threadIdx.x;
    if (bid < 1024) {
        int i = bid * 256 + tid;
        const int stride = 1024 * 256;
        const int n4 = 4096 * 1024 / 4;
        for (; i < n4; i += stride) {
            float4 f = reinterpret_cast<const float4*>(x)[i];
            ushort4 o;
            o.x = f2bf(f.x); o.y = f2bf(f.y); o.z = f2bf(f.z); o.w = f2bf(f.w);
            reinterpret_cast<ushort4*>(xb)[i] = o;
        }
        return;
    }
    if (bid < 4096) {
        int idx = bid - 1024;
        int cx = idx % 96, ry = idx / 96;
        int c0 = cx * 32, r0 = ry * 32;
        int tx = tid & 31, ty = tid >> 5;
#pragma unroll
        for (int i = 0; i < 32; i += 8)
            tile[ty + i][tx] = f2bf(w_qkv[(size_t)(r0 + ty + i) * 3072 + c0 + tx]);
        __syncthreads();
#pragma unroll
        for (int i = 0; i < 32; i += 8)
            wqkvT[(size_t)(c0 + ty + i) * 1024 + r0 + tx] = tile[tx][ty + i];
        return;
    }
    {
        int idx = bid - 4096;
        int cx = idx % 32, ry = idx / 32;
        int c0 = cx * 32, r0 = ry * 32;
        int tx = tid & 31, ty = tid >> 5;
#pragma unroll
        for (int i = 0; i < 32; i += 8)
            tile[ty + i][tx] = f2bf(w_out[(size_t)(r0 + ty + i) * 1024 + c0 + tx]);
        __syncthreads();
#pragma unroll
        for (int i = 0; i < 32; i += 8)
            woutT[(size_t)(c0 + ty + i) * 1024 + r0 + tx] = tile[tx][ty + i];
    }
}

// ---------- kernel 2b: per-(b,h) V transpose ----------
__global__ void transpose_v(const ushort_t* __restrict__ qkv, ushort_t* __restrict__ vt) {
    __shared__ ushort_t tile[32][33];
    int s0 = blockIdx.x * 32, d0 = blockIdx.y * 32;
    int bh = blockIdx.z;                        // b*16+h
    int b = bh >> 4, h = bh & 15;
    const ushort_t* src = qkv + (size_t)(b * SQ) * 3072 + 2048 + h * 64;
    ushort_t* dst = vt + (size_t)bh * HD * SQ;
    int tx = threadIdx.x, ty = threadIdx.y;     // block (32,8)
#pragma unroll
    for (int i = 0; i < 32; i += 8)
        tile[ty + i][tx] = src[(size_t)(s0 + ty + i) * 3072 + d0 + tx];
    __syncthreads();
#pragma unroll
    for (int i = 0; i < 32; i += 8)
        dst[(size_t)(d0 + ty + i) * SQ + s0 + tx] = tile[tx][ty + i];
}

// =====================================================================
// GEMM1: 256x192 tile, 4-phase counted-vmcnt, 256 blocks (1/CU).
// =====================================================================

#define STAGE_U(Gptr, ldk, grow0, kcol, regionbase)                          \
  { int row_ = tid >> 3;                                                      \
    int sc_ = (tid & 7) ^ (row_ & 7);                                         \
    load_lds16((Gptr) + (size_t)((grow0) + row_) * (ldk) + (kcol) + sc_ * 8,  \
               (regionbase) + tid * 16); }

#define DS_A192(BASE, EXTRA)                                                  \
  _Pragma("unroll") for (int kk_ = 0; kk_ < 2; ++kk_)                         \
  _Pragma("unroll") for (int m_ = 0; m_ < 4; ++m_)                            \
    a[kk_][m_] = *reinterpret_cast<const bf16x8*>((BASE) + (EXTRA) + offA[kk_][m_]);

#define DS_B192(BASE)                                                         \
  _Pragma("unroll") for (int kk_ = 0; kk_ < 2; ++kk_)                         \
  _Pragma("unroll") for (int n_ = 0; n_ < 3; ++n_)                            \
    b[kk_][n_] = *reinterpret_cast<const bf16x8*>((BASE) + offB[kk_][n_]);

#define BAR_LGKM                                                              \
  __builtin_amdgcn_s_barrier();                                               \
  asm volatile("s_waitcnt lgkmcnt(0)" ::: "memory");                          \
  __builtin_amdgcn_sched_barrier(0);

#define MFMA_Q(MQ)                                                            \
  __builtin_amdgcn_s_setprio(1);                                              \
  _Pragma("unroll") for (int kk_ = 0; kk_ < 2; ++kk_)                         \
  _Pragma("unroll") for (int m_ = 0; m_ < 4; ++m_)                            \
  _Pragma("unroll") for (int n_ = 0; n_ < 3; ++n_)                            \
    acc[(MQ)*4 + m_][n_] = __builtin_amdgcn_mfma_f32_16x16x32_bf16(           \
        a[kk_][m_], b[kk_][n_], acc[(MQ)*4 + m_][n_], 0, 0, 0);               \
  __builtin_amdgcn_s_setprio(0);

__global__ __launch_bounds__(512, 2)
void gemm192_bt(const ushort_t* __restrict__ A, const ushort_t* __restrict__ Bt,
                const float* __restrict__ bias, ushort_t* __restrict__ Cout,
                int M, int N, int K, int nbn) {
    __shared__ char sm[114688];
    const int tid = threadIdx.x;
    const int lane = tid & 63;
    const int w = tid >> 6;                 // 0..7
    const int wm = w >> 2, wn = w & 3;      // 2M x 4N waves
    const int r = lane & 15, hi = lane >> 4;

    const int cpx = gridDim.x >> 3;
    const int bid = blockIdx.x;
    const int x = (bid & 7) * cpx + (bid >> 3);
    const int bm = x / nbn, bn = x % nbn;
    const int m0 = bm * 256, n0 = bn * 192;

    const int NT = K >> 6;                  // 16 K-tiles
    const int NI = NT >> 1;                 // 8 iterations

    char* const A0 = sm;
    char* const B0 = sm + 32768;
    char* const A1 = sm + 57344;
    char* const B1 = sm + 90112;

    int offA[2][4], offB[2][3];
#pragma unroll
    for (int kk = 0; kk < 2; ++kk) {
#pragma unroll
        for (int m = 0; m < 4; ++m) {
            int rowL = wm * 128 + m * 16 + r;
            offA[kk][m] = rowL * 128 + (((kk * 4 + hi) ^ (rowL & 7)) * 16);
        }
#pragma unroll
        for (int n = 0; n < 3; ++n) {
            int rowL = wn * 48 + n * 16 + r;
            offB[kk][n] = rowL * 128 + (((kk * 4 + hi) ^ (rowL & 7)) * 16);
        }
    }

    f32x4 acc[8][3];
#pragma unroll
    for (int am = 0; am < 8; ++am)
#pragma unroll
        for (int an = 0; an < 3; ++an) acc[am][an] = (f32x4){0.f, 0.f, 0.f, 0.f};

    bf16x8 a[2][4], b[2][3];

    STAGE_U(A,  K, m0,        0, A0);
    STAGE_U(A,  K, m0 + 64,   0, A0 + 8192);
    STAGE_U(A,  K, m0 + 128,  0, A0 + 16384);
    STAGE_U(A,  K, m0 + 192,  0, A0 + 24576);
    STAGE_U(Bt, K, n0,        0, B0);
    STAGE_U(Bt, K, n0 + 64,   0, B0 + 8192);
    STAGE_U(Bt, K, n0 + 128,  0, B0 + 16384);
    STAGE_U(A,  K, m0,       64, A1);
    STAGE_U(A,  K, m0 + 128, 64, A1 + 16384);
    asm volatile("s_waitcnt vmcnt(2)" ::: "memory");
    __builtin_amdgcn_s_barrier();

    for (int i = 0; i < NI; ++i) {
        const int k1 = (2 * i + 1) * 64;
        const int k2 = ((2 * i + 2) % NT) * 64;
        const int k3 = ((2 * i + 3) % NT) * 64;

        STAGE_U(A,  K, m0 + 64,  k1, A1 + 8192);
        STAGE_U(A,  K, m0 + 192, k1, A1 + 24576);
        STAGE_U(Bt, K, n0,       k1, B1);
        STAGE_U(Bt, K, n0 + 64,  k1, B1 + 8192);
        STAGE_U(Bt, K, n0 + 128, k1, B1 + 16384);
        DS_A192(A0, 0); DS_B192(B0);
        BAR_LGKM; MFMA_Q(0);
        __builtin_amdgcn_s_barrier();

        STAGE_U(A, K, m0,       k2, A0);
        STAGE_U(A, K, m0 + 128, k2, A0 + 16384);
        DS_A192(A0, 8192);
        BAR_LGKM; MFMA_Q(1);
        asm volatile("s_waitcnt vmcnt(2)" ::: "memory");
        __builtin_amdgcn_s_barrier();

        STAGE_U(A,  K, m0 + 64,  k2, A0 + 8192);
        STAGE_U(A,  K, m0 + 192, k2, A0 + 24576);
        STAGE_U(Bt, K, n0,       k2, B0);
        STAGE_U(Bt, K, n0 + 64,  k2, B0 + 8192);
        STAGE_U(Bt, K, n0 + 128, k2, B0 + 16384);
        DS_A192(A1, 0); DS_B192(B1);
        BAR_LGKM; MFMA_Q(0);
        __builtin_amdgcn_s_barrier();

        STAGE_U(A, K, m0,       k3, A1);
        STAGE_U(A, K, m0 + 128, k3, A1 + 16384);
        DS_A192(A1, 8192);
        BAR_LGKM; MFMA_Q(1);
        asm volatile("s_waitcnt vmcnt(2)" ::: "memory");
        __builtin_amdgcn_s_barrier();
    }

#pragma unroll
    for (int am = 0; am < 8; ++am) {
        int rowg = m0 + wm * 128 + (am >> 2) * 64 + (am & 3) * 16 + hi * 4;
#pragma unroll
        for (int an = 0; an < 3; ++an) {
            int colg = n0 + wn * 48 + an * 16 + r;
            float bv = bias[colg];
#pragma unroll
            for (int j = 0; j < 4; ++j) {
                float v = acc[am][an][j] + bv;
                Cout[(size_t)(rowg + j) * N + colg] = f2bf(v);
            }
        }
    }
}

// =====================================================================
// GEMM2: 128x128 tile, 4-phase counted-vmcnt, 512 threads (8 waves), 256 blocks.
// =====================================================================

#define G2_DSA(BASE, MQ)                                                      \
  _Pragma("unroll") for (int kk_ = 0; kk_ < 2; ++kk_)                         \
  _Pragma("unroll") for (int m_ = 0; m_ < 2; ++m_)                            \
    a2[kk_][m_] = *reinterpret_cast<const bf16x8*>((BASE) + offA2[kk_][(MQ)*2 + m_]);

#define G2_DSB(BASE)                                                          \
  _Pragma("unroll") for (int kk_ = 0; kk_ < 2; ++kk_)                         \
  _Pragma("unroll") for (int n_ = 0; n_ < 2; ++n_)                            \
    b2[kk_][n_] = *reinterpret_cast<const bf16x8*>((BASE) + offB2[kk_][n_]);

#define G2_MFMA(MQ)                                                           \
  __builtin_amdgcn_s_setprio(1);                                              \
  _Pragma("unroll") for (int kk_ = 0; kk_ < 2; ++kk_)                         \
  _Pragma("unroll") for (int m_ = 0; m_ < 2; ++m_)                            \
  _Pragma("unroll") for (int n_ = 0; n_ < 2; ++n_)                            \
    acc[(MQ)*2 + m_][n_] = __builtin_amdgcn_mfma_f32_16x16x32_bf16(           \
        a2[kk_][m_], b2[kk_][n_], acc[(MQ)*2 + m_][n_], 0, 0, 0);             \
  __builtin_amdgcn_s_setprio(0);

__global__ __launch_bounds__(512, 2)
void gemm128_4ph(const ushort_t* __restrict__ A, const ushort_t* __restrict__ Bt,
                 const float* __restrict__ bias, float* __restrict__ Cout,
                 int M, int N, int K, int nbn) {
    __shared__ char sm[65536];
    const int tid = threadIdx.x;
    const int lane = tid & 63;
    const int w = tid >> 6;
    const int wm = w >> 2, wn = w & 3;      // 2M x 4N
    const int r = lane & 15, hi = lane >> 4;

    const int cpx = gridDim.x >> 3;
    const int bid = blockIdx.x;
    const int x = (bid & 7) * cpx + (bid >> 3);
    const int bm = x / nbn, bn = x % nbn;
    const int m0 = bm * 128, n0 = bn * 128;

    const int NT = K >> 6;                  // 16
    const int NI = NT >> 1;                 // 8

    char* const A0 = sm;
    char* const B0 = sm + 16384;
    char* const A1 = sm + 32768;
    char* const B1 = sm + 49152;

    int offA2[2][4], offB2[2][2];
#pragma unroll
    for (int kk = 0; kk < 2; ++kk) {
#pragma unroll
        for (int m = 0; m < 4; ++m) {
            int rowL = wm * 64 + m * 16 + r;
            offA2[kk][m] = rowL * 128 + (((kk * 4 + hi) ^ (rowL & 7)) * 16);
        }
#pragma unroll
        for (int n = 0; n < 2; ++n) {
            int rowL = wn * 32 + n * 16 + r;
            offB2[kk][n] = rowL * 128 + (((kk * 4 + hi) ^ (rowL & 7)) * 16);
        }
    }

    f32x4 acc[4][2];
#pragma unroll
    for (int am = 0; am < 4; ++am)
#pragma unroll
        for (int an = 0; an < 2; ++an) acc[am][an] = (f32x4){0.f, 0.f, 0.f, 0.f};

    bf16x8 a2[2][2], b2[2][2];

    STAGE_U(A,  K, m0,       0, A0);
    STAGE_U(A,  K, m0 + 64,  0, A0 + 8192);
    STAGE_U(Bt, K, n0,       0, B0);
    STAGE_U(Bt, K, n0 + 64,  0, B0 + 8192);
    STAGE_U(Bt, K, n0,      64, B1);
    STAGE_U(Bt, K, n0 + 64, 64, B1 + 8192);
    asm volatile("s_waitcnt vmcnt(2)" ::: "memory");
    __builtin_amdgcn_s_barrier();

    for (int i = 0; i < NI; ++i) {
        const int k1 = (2 * i + 1) * 64;
        const int k2 = ((2 * i + 2) % NT) * 64;
        const int k3 = ((2 * i + 3) % NT) * 64;

        STAGE_U(A, K, m0,      k1, A1);
        STAGE_U(A, K, m0 + 64, k1, A1 + 8192);
        G2_DSA(A0, 0); G2_DSB(B0);
        BAR_LGKM; G2_MFMA(0);
        __builtin_amdgcn_s_barrier();

        STAGE_U(Bt, K, n0,      k2, B0);
        STAGE_U(Bt, K, n0 + 64, k2, B0 + 8192);
        G2_DSA(A0, 1);
        BAR_LGKM; G2_MFMA(1);
        asm volatile("s_waitcnt vmcnt(2)" ::: "memory");
        __builtin_amdgcn_s_barrier();

        STAGE_U(A, K, m0,      k2, A0);
        STAGE_U(A, K, m0 + 64, k2, A0 + 8192);
        G2_DSA(A1, 0); G2_DSB(B1);
        BAR_LGKM; G2_MFMA(0);
        __builtin_amdgcn_s_barrier();

        STAGE_U(Bt, K, n0,      k3, B1);
        STAGE_U(Bt, K, n0 + 64, k3, B1 + 8192);
        G2_DSA(A1, 1);
        BAR_LGKM; G2_MFMA(1);
        asm volatile("s_waitcnt vmcnt(2)" ::: "memory");
        __builtin_amdgcn_s_barrier();
    }

#pragma unroll
    for (int am = 0; am < 4; ++am) {
        int rowg = m0 + wm * 64 + am * 16 + hi * 4;
#pragma unroll
        for (int an = 0; an < 2; ++an) {
            int colg = n0 + wn * 32 + an * 16 + r;
            float bv = bias[colg];
#pragma unroll
            for (int j = 0; j < 4; ++j)
                Cout[(size_t)(rowg + j) * N + colg] = acc[am][an][j] + bv;
        }
    }
}

// ---------- banded attention v3 (best-measured): 2 barriers, P aliases K,
// V^T staged; 50176B LDS. ----------
__global__ __launch_bounds__(256, 4)
void attn_kernel(const ushort_t* __restrict__ qkv, const ushort_t* __restrict__ vt,
                 ushort_t* __restrict__ attn_out) {
    __shared__ uint4 smem4[50176 / 16];
    char* smem = (char*)smem4;

    const int bid0 = blockIdx.x;
    const int bid = (bid0 & 7) * 128 + (bid0 >> 3);   // XCD-chunked
    const int qb = bid & 31;
    const int h = (bid >> 5) & 15;
    const int b = bid >> 9;
    const int q0 = qb * 64;
    const int kstart = (q0 - 64 > 0) ? (q0 - 64) : 0;

    const int tid = threadIdx.x;
    const int lane = tid & 63;
    const int w = tid >> 6;
    const int r = lane & 15, hi = lane >> 4;

    // ---- stage K [192][64] @0 (swizzled, zero-fill OOB) ----
#pragma unroll
    for (int i = 0; i < 6; ++i) {
        int task = i * 256 + tid;
        int row = task >> 3, ch = task & 7;
        int key = kstart + row;
        uint4 v = make_uint4(0u, 0u, 0u, 0u);
        if (key < SQ)
            v = *reinterpret_cast<const uint4*>(
                qkv + (size_t)(b * SQ + key) * 3072 + 1024 + h * 64 + ch * 8);
        int byte = row * 128 + ch * 16; byte ^= (row & 7) << 4;
        *reinterpret_cast<uint4*>(smem + byte) = v;
    }
    // ---- stage V^T [64 d][192 k] @25600 from pre-transposed vt ----
    {
        const ushort_t* vtb = vt + (size_t)(b * NH + h) * HD * SQ;
        int d = tid >> 2, cp = tid & 3;
#pragma unroll
        for (int i = 0; i < 6; ++i) {
            int c = cp + i * 4;                 // chunk 0..23 (16B each, 8 keys)
            uint4 v = make_uint4(0u, 0u, 0u, 0u);
            int k8 = kstart + c * 8;
            if (k8 < SQ)
                v = *reinterpret_cast<const uint4*>(vtb + (size_t)d * SQ + k8);
            int byte = d * 384 + (((c & 7) ^ (d & 7)) * 16) + ((c >> 3) * 128);
            *reinterpret_cast<uint4*>(smem + 25600 + byte) = v;
        }
    }

    // ---- Q directly into A-fragments ----
    const ushort_t* qrow = qkv + (size_t)(b * SQ + q0 + w * 16 + r) * 3072 + h * 64;
    bf16x8 aq0 = *reinterpret_cast<const bf16x8*>(qrow + hi * 8);
    bf16x8 aq1 = *reinterpret_cast<const bf16x8*>(qrow + 32 + hi * 8);

    __syncthreads();   // barrier #1: staging complete

    const int delta = q0 - kstart;
    const int base = w * 16 + delta;
    int tmin = (base - 64) >> 4; if (tmin < 0) tmin = 0;
    int tmax = (base + 79) >> 4;
    int tcap = (SQ - 1 - kstart) >> 4; if (tmax > tcap) tmax = tcap;
    if (tmax > 11) tmax = 11;
    const int ksmin = tmin >> 1, ksmax = tmax >> 1;

    f32x4 acc[12];
#pragma unroll
    for (int t = 0; t < 12; ++t) acc[t] = (f32x4){0.f, 0.f, 0.f, 0.f};
#pragma unroll
    for (int t = 0; t < 12; ++t) {
        if (t < tmin || t > tmax) continue;
#pragma unroll
        for (int ks = 0; ks < 2; ++ks) {
            int row = t * 16 + r;
            int byte = row * 128 + ks * 64 + hi * 16; byte ^= (row & 7) << 4;
            bf16x8 bk = *reinterpret_cast<const bf16x8*>(smem + byte);
            acc[t] = __builtin_amdgcn_mfma_f32_16x16x32_bf16(
                ks == 0 ? aq0 : aq1, bk, acc[t], 0, 0, 0);
        }
    }

    float mrow[4], lrow[4];
#pragma unroll
    for (int t = 0; t < 12; ++t) {
        if (t < tmin || t > tmax) continue;
        int key = kstart + t * 16 + r;
#pragma unroll
        for (int j = 0; j < 4; ++j) {
            int qrow_g = q0 + w * 16 + hi * 4 + j;
            int dd = key - qrow_g; if (dd < 0) dd = -dd;
            bool valid = (key < SQ) && (dd <= 64);
            acc[t][j] = valid ? acc[t][j] * 0.125f : -1e30f;
        }
    }
#pragma unroll
    for (int j = 0; j < 4; ++j) {
        float m = -1e30f;
#pragma unroll
        for (int t = 0; t < 12; ++t) {
            if (t < tmin || t > tmax) continue;
            m = fmaxf(m, acc[t][j]);
        }
        m = fmaxf(m, __shfl_xor(m, 1));
        m = fmaxf(m, __shfl_xor(m, 2));
        m = fmaxf(m, __shfl_xor(m, 4));
        m = fmaxf(m, __shfl_xor(m, 8));
        mrow[j] = m;
    }
#pragma unroll
    for (int j = 0; j < 4; ++j) {
        float s = 0.f;
#pragma unroll
        for (int t = 0; t < 12; ++t) {
            if (t < tmin || t > tmax) continue;
            float p = __expf(acc[t][j] - mrow[j]);
            acc[t][j] = p;
            s += p;
        }
        s += __shfl_xor(s, 1);
        s += __shfl_xor(s, 2);
        s += __shfl_xor(s, 4);
        s += __shfl_xor(s, 8);
        lrow[j] = s;
    }

    __syncthreads();   // barrier #2: all QK^T reads of K done; P may overwrite

#pragma unroll
    for (int t = 0; t < 12; ++t) {
        int col = t * 16 + r;
        bool inb = (t >= tmin) && (t <= tmax);
#pragma unroll
        for (int j = 0; j < 4; ++j) {
            int rowL = w * 16 + hi * 4 + j;
            ushort_t pv = inb ? f2bf(acc[t][j]) : (ushort_t)0;
            *reinterpret_cast<ushort_t*>(smem + rowL * 400 + col * 2) = pv;
        }
    }
    // same-wave write->read dependency: compiler inserts lgkmcnt; no barrier.

    f32x4 oacc[4];
#pragma unroll
    for (int dt = 0; dt < 4; ++dt) oacc[dt] = (f32x4){0.f, 0.f, 0.f, 0.f};
#pragma unroll
    for (int ks = 0; ks < 6; ++ks) {
        if (ks < ksmin || ks > ksmax) continue;
        int k0 = ks * 32 + hi * 8;
        bf16x8 ap = *reinterpret_cast<const bf16x8*>(
            smem + (w * 16 + r) * 400 + k0 * 2);
        int cch = ks * 4 + hi;                  // 16B chunk index 0..23
#pragma unroll
        for (int dt = 0; dt < 4; ++dt) {
            int d = dt * 16 + r;
            int byte = d * 384 + (((cch & 7) ^ (d & 7)) * 16) + ((cch >> 3) * 128);
            bf16x8 bv = *reinterpret_cast<const bf16x8*>(smem + 25600 + byte);
            oacc[dt] = __builtin_amdgcn_mfma_f32_16x16x32_bf16(ap, bv, oacc[dt], 0, 0, 0);
        }
    }

    float inv[4];
#pragma unroll
    for (int j = 0; j < 4; ++j) inv[j] = 1.0f / lrow[j];
#pragma unroll
    for (int dt = 0; dt < 4; ++dt) {
        int d = dt * 16 + r;
#pragma unroll
        for (int j = 0; j < 4; ++j) {
            int q = q0 + w * 16 + hi * 4 + j;
            attn_out[(size_t)(b * SQ + q) * 1024 + h * 64 + d] = f2bf(oacc[dt][j] * inv[j]);
        }
    }
}

// ---------- launch ----------
extern "C" void kernel_launch(void* const* d_in, const int* in_sizes, int n_in,
                              void* d_out, int out_size, void* d_ws, size_t ws_size,
                              hipStream_t stream) {
    const float* x     = (const float*)d_in[0];
    const float* w_qkv = (const float*)d_in[1];
    const float* b_qkv = (const float*)d_in[2];
    const float* w_out = (const float*)d_in[3];
    const float* b_out = (const float*)d_in[4];
    float* out = (float*)d_out;

    char* ws = (char*)d_ws;
    ushort_t* xb    = (ushort_t*)(ws);                       // 8 MB  [4096][1024]
    ushort_t* wqkvT = (ushort_t*)(ws + 8388608);             // 6 MB  [3072][1024]
    ushort_t* woutT = (ushort_t*)(ws + 14680064);            // 2 MB  [1024][1024]
    ushort_t* qkv   = (ushort_t*)(ws + 16777216);            // 24 MB [4096][3072]
    ushort_t* aout  = (ushort_t*)(ws + 41943040);            // 8 MB  [4096][1024]
    ushort_t* vtbuf = (ushort_t*)(ws + 50331648);            // 8 MB  [32][64][2048]

    prep_kernel<<<5120, 256, 0, stream>>>(x, xb, w_qkv, wqkvT, w_out, woutT);

    gemm192_bt<<<256, 512, 0, stream>>>(xb, wqkvT, b_qkv, qkv, 4096, 3072, 1024, 16);
    transpose_v<<<dim3(64, 2, 32), dim3(32, 8), 0, stream>>>(qkv, vtbuf);
    attn_kernel<<<1024, 256, 0, stream>>>(qkv, vtbuf, aout);
    gemm128_4ph<<<256, 512, 0, stream>>>(aout, woutT, b_out, out, 4096, 1024, 1024, 8);
}

// Round 18
// 75.133 us; speedup vs baseline: 1.0710x; 1.0386x over previous
//
#include <hip/hip_runtime.h>
#include <hip/hip_bf16.h>

// ---------- types ----------
typedef short bf16x8 __attribute__((ext_vector_type(8)));   // 8 bf16 = 4 VGPR
typedef float f32x4 __attribute__((ext_vector_type(4)));
typedef unsigned short ushort_t;

#define SQ 2048
#define DIM 1024
#define NH 16
#define HD 64

__device__ __forceinline__ ushort_t f2bf(float f) {
    __hip_bfloat16 h = __float2bfloat16(f);     // HW v_cvt, RNE
    return *reinterpret_cast<ushort_t*>(&h);
}

__device__ __forceinline__ void load_lds16(const void* g, void* l) {
    __builtin_amdgcn_global_load_lds(
        (const __attribute__((address_space(1))) unsigned int*)g,
        (__attribute__((address_space(3))) unsigned int*)l, 16, 0, 0);
}

// ---------- fused prep: cvt_x | transpose(w_qkv) | transpose(w_out) ----------
__global__ void prep_kernel(const float* __restrict__ x, ushort_t* __restrict__ xb,
                            const float* __restrict__ w_qkv, ushort_t* __restrict__ wqkvT,
                            const float* __restrict__ w_out, ushort_t* __restrict__ woutT) {
    __shared__ ushort_t tile[32][33];
    const int bid = blockIdx.x;
    const int tid = threadIdx.x;
    if (bid < 1024) {
        int i = bid * 256 + tid;
        const int stride = 1024 * 256;
        const int n4 = 4096 * 1024 / 4;
        for (; i < n4; i += stride) {
            float4 f = reinterpret_cast<const float4*>(x)[i];
            ushort4 o;
            o.x = f2bf(f.x); o.y = f2bf(f.y); o.z = f2bf(f.z); o.w = f2bf(f.w);
            reinterpret_cast<ushort4*>(xb)[i] = o;
        }
        return;
    }
    if (bid < 4096) {
        int idx = bid - 1024;
        int cx = idx % 96, ry = idx / 96;
        int c0 = cx * 32, r0 = ry * 32;
        int tx = tid & 31, ty = tid >> 5;
#pragma unroll
        for (int i = 0; i < 32; i += 8)
            tile[ty + i][tx] = f2bf(w_qkv[(size_t)(r0 + ty + i) * 3072 + c0 + tx]);
        __syncthreads();
#pragma unroll
        for (int i = 0; i < 32; i += 8)
            wqkvT[(size_t)(c0 + ty + i) * 1024 + r0 + tx] = tile[tx][ty + i];
        return;
    }
    {
        int idx = bid - 4096;
        int cx = idx % 32, ry = idx / 32;
        int c0 = cx * 32, r0 = ry * 32;
        int tx = tid & 31, ty = tid >> 5;
#pragma unroll
        for (int i = 0; i < 32; i += 8)
            tile[ty + i][tx] = f2bf(w_out[(size_t)(r0 + ty + i) * 1024 + c0 + tx]);
        __syncthreads();
#pragma unroll
        for (int i = 0; i < 32; i += 8)
            woutT[(size_t)(c0 + ty + i) * 1024 + r0 + tx] = tile[tx][ty + i];
    }
}

// =====================================================================
// GEMM1: 256x192 tile, 4-phase counted-vmcnt, 256 blocks (1/CU).
// Epilogue writes Q/K columns to qkv, V columns (colg>=2048) DIRECTLY
// TRANSPOSED into vtbuf (8B-contiguous per lane, wave-uniform branch)
// -> transpose_v kernel eliminated.
// =====================================================================

#define STAGE_U(Gptr, ldk, grow0, kcol, regionbase)                          \
  { int row_ = tid >> 3;                                                      \
    int sc_ = (tid & 7) ^ (row_ & 7);                                         \
    load_lds16((Gptr) + (size_t)((grow0) + row_) * (ldk) + (kcol) + sc_ * 8,  \
               (regionbase) + tid * 16); }

#define DS_A192(BASE, EXTRA)                                                  \
  _Pragma("unroll") for (int kk_ = 0; kk_ < 2; ++kk_)                         \
  _Pragma("unroll") for (int m_ = 0; m_ < 4; ++m_)                            \
    a[kk_][m_] = *reinterpret_cast<const bf16x8*>((BASE) + (EXTRA) + offA[kk_][m_]);

#define DS_B192(BASE)                                                         \
  _Pragma("unroll") for (int kk_ = 0; kk_ < 2; ++kk_)                         \
  _Pragma("unroll") for (int n_ = 0; n_ < 3; ++n_)                            \
    b[kk_][n_] = *reinterpret_cast<const bf16x8*>((BASE) + offB[kk_][n_]);

#define BAR_LGKM                                                              \
  __builtin_amdgcn_s_barrier();                                               \
  asm volatile("s_waitcnt lgkmcnt(0)" ::: "memory");                          \
  __builtin_amdgcn_sched_barrier(0);

#define MFMA_Q(MQ)                                                            \
  __builtin_amdgcn_s_setprio(1);                                              \
  _Pragma("unroll") for (int kk_ = 0; kk_ < 2; ++kk_)                         \
  _Pragma("unroll") for (int m_ = 0; m_ < 4; ++m_)                            \
  _Pragma("unroll") for (int n_ = 0; n_ < 3; ++n_)                            \
    acc[(MQ)*4 + m_][n_] = __builtin_amdgcn_mfma_f32_16x16x32_bf16(           \
        a[kk_][m_], b[kk_][n_], acc[(MQ)*4 + m_][n_], 0, 0, 0);               \
  __builtin_amdgcn_s_setprio(0);

__global__ __launch_bounds__(512, 2)
void gemm192_bt(const ushort_t* __restrict__ A, const ushort_t* __restrict__ Bt,
                const float* __restrict__ bias, ushort_t* __restrict__ Cout,
                ushort_t* __restrict__ vtbuf,
                int M, int N, int K, int nbn) {
    __shared__ char sm[114688];
    const int tid = threadIdx.x;
    const int lane = tid & 63;
    const int w = tid >> 6;                 // 0..7
    const int wm = w >> 2, wn = w & 3;      // 2M x 4N waves
    const int r = lane & 15, hi = lane >> 4;

    const int cpx = gridDim.x >> 3;
    const int bid = blockIdx.x;
    const int x = (bid & 7) * cpx + (bid >> 3);
    const int bm = x / nbn, bn = x % nbn;
    const int m0 = bm * 256, n0 = bn * 192;

    const int NT = K >> 6;                  // 16 K-tiles
    const int NI = NT >> 1;                 // 8 iterations

    char* const A0 = sm;
    char* const B0 = sm + 32768;
    char* const A1 = sm + 57344;
    char* const B1 = sm + 90112;

    int offA[2][4], offB[2][3];
#pragma unroll
    for (int kk = 0; kk < 2; ++kk) {
#pragma unroll
        for (int m = 0; m < 4; ++m) {
            int rowL = wm * 128 + m * 16 + r;
            offA[kk][m] = rowL * 128 + (((kk * 4 + hi) ^ (rowL & 7)) * 16);
        }
#pragma unroll
        for (int n = 0; n < 3; ++n) {
            int rowL = wn * 48 + n * 16 + r;
            offB[kk][n] = rowL * 128 + (((kk * 4 + hi) ^ (rowL & 7)) * 16);
        }
    }

    f32x4 acc[8][3];
#pragma unroll
    for (int am = 0; am < 8; ++am)
#pragma unroll
        for (int an = 0; an < 3; ++an) acc[am][an] = (f32x4){0.f, 0.f, 0.f, 0.f};

    bf16x8 a[2][4], b[2][3];

    STAGE_U(A,  K, m0,        0, A0);
    STAGE_U(A,  K, m0 + 64,   0, A0 + 8192);
    STAGE_U(A,  K, m0 + 128,  0, A0 + 16384);
    STAGE_U(A,  K, m0 + 192,  0, A0 + 24576);
    STAGE_U(Bt, K, n0,        0, B0);
    STAGE_U(Bt, K, n0 + 64,   0, B0 + 8192);
    STAGE_U(Bt, K, n0 + 128,  0, B0 + 16384);
    STAGE_U(A,  K, m0,       64, A1);
    STAGE_U(A,  K, m0 + 128, 64, A1 + 16384);
    asm volatile("s_waitcnt vmcnt(2)" ::: "memory");
    __builtin_amdgcn_s_barrier();

    for (int i = 0; i < NI; ++i) {
        const int k1 = (2 * i + 1) * 64;
        const int k2 = ((2 * i + 2) % NT) * 64;
        const int k3 = ((2 * i + 3) % NT) * 64;

        STAGE_U(A,  K, m0 + 64,  k1, A1 + 8192);
        STAGE_U(A,  K, m0 + 192, k1, A1 + 24576);
        STAGE_U(Bt, K, n0,       k1, B1);
        STAGE_U(Bt, K, n0 + 64,  k1, B1 + 8192);
        STAGE_U(Bt, K, n0 + 128, k1, B1 + 16384);
        DS_A192(A0, 0); DS_B192(B0);
        BAR_LGKM; MFMA_Q(0);
        __builtin_amdgcn_s_barrier();

        STAGE_U(A, K, m0,       k2, A0);
        STAGE_U(A, K, m0 + 128, k2, A0 + 16384);
        DS_A192(A0, 8192);
        BAR_LGKM; MFMA_Q(1);
        asm volatile("s_waitcnt vmcnt(2)" ::: "memory");
        __builtin_amdgcn_s_barrier();

        STAGE_U(A,  K, m0 + 64,  k2, A0 + 8192);
        STAGE_U(A,  K, m0 + 192, k2, A0 + 24576);
        STAGE_U(Bt, K, n0,       k2, B0);
        STAGE_U(Bt, K, n0 + 64,  k2, B0 + 8192);
        STAGE_U(Bt, K, n0 + 128, k2, B0 + 16384);
        DS_A192(A1, 0); DS_B192(B1);
        BAR_LGKM; MFMA_Q(0);
        __builtin_amdgcn_s_barrier();

        STAGE_U(A, K, m0,       k3, A1);
        STAGE_U(A, K, m0 + 128, k3, A1 + 16384);
        DS_A192(A1, 8192);
        BAR_LGKM; MFMA_Q(1);
        asm volatile("s_waitcnt vmcnt(2)" ::: "memory");
        __builtin_amdgcn_s_barrier();
    }

    // ---- epilogue: Q/K cols -> qkv; V cols (colg>=2048) -> vtbuf transposed.
    //      colg base is a multiple of 16 and 2048 % 16 == 0 -> branch is
    //      wave-uniform. V path: j=0..3 are 4 consecutive s -> 8B store.
#pragma unroll
    for (int am = 0; am < 8; ++am) {
        int rowg = m0 + wm * 128 + (am >> 2) * 64 + (am & 3) * 16 + hi * 4;
#pragma unroll
        for (int an = 0; an < 3; ++an) {
            int colg = n0 + wn * 48 + an * 16 + r;
            float bv = bias[colg];
            if (colg < 2048) {
#pragma unroll
                for (int j = 0; j < 4; ++j)
                    Cout[(size_t)(rowg + j) * N + colg] = f2bf(acc[am][an][j] + bv);
            } else {
                int hh = (colg - 2048) >> 6;
                int d  = (colg - 2048) & 63;
                int bb = rowg >> 11;            // 2048 rows per batch
                int s  = rowg & 2047;           // block rows never straddle b
                ushort_t* dst = vtbuf + ((size_t)(bb * NH + hh) * HD + d) * SQ + s;
#pragma unroll
                for (int j = 0; j < 4; ++j)
                    dst[j] = f2bf(acc[am][an][j] + bv);
            }
        }
    }
}

// =====================================================================
// GEMM2: 128x128 tile, 4-phase counted-vmcnt, 512 threads (8 waves), 256 blocks.
// =====================================================================

#define G2_DSA(BASE, MQ)                                                      \
  _Pragma("unroll") for (int kk_ = 0; kk_ < 2; ++kk_)                         \
  _Pragma("unroll") for (int m_ = 0; m_ < 2; ++m_)                            \
    a2[kk_][m_] = *reinterpret_cast<const bf16x8*>((BASE) + offA2[kk_][(MQ)*2 + m_]);

#define G2_DSB(BASE)                                                          \
  _Pragma("unroll") for (int kk_ = 0; kk_ < 2; ++kk_)                         \
  _Pragma("unroll") for (int n_ = 0; n_ < 2; ++n_)                            \
    b2[kk_][n_] = *reinterpret_cast<const bf16x8*>((BASE) + offB2[kk_][n_]);

#define G2_MFMA(MQ)                                                           \
  __builtin_amdgcn_s_setprio(1);                                              \
  _Pragma("unroll") for (int kk_ = 0; kk_ < 2; ++kk_)                         \
  _Pragma("unroll") for (int m_ = 0; m_ < 2; ++m_)                            \
  _Pragma("unroll") for (int n_ = 0; n_ < 2; ++n_)                            \
    acc[(MQ)*2 + m_][n_] = __builtin_amdgcn_mfma_f32_16x16x32_bf16(           \
        a2[kk_][m_], b2[kk_][n_], acc[(MQ)*2 + m_][n_], 0, 0, 0);             \
  __builtin_amdgcn_s_setprio(0);

__global__ __launch_bounds__(512, 2)
void gemm128_4ph(const ushort_t* __restrict__ A, const ushort_t* __restrict__ Bt,
                 const float* __restrict__ bias, float* __restrict__ Cout,
                 int M, int N, int K, int nbn) {
    __shared__ char sm[65536];
    const int tid = threadIdx.x;
    const int lane = tid & 63;
    const int w = tid >> 6;
    const int wm = w >> 2, wn = w & 3;      // 2M x 4N
    const int r = lane & 15, hi = lane >> 4;

    const int cpx = gridDim.x >> 3;
    const int bid = blockIdx.x;
    const int x = (bid & 7) * cpx + (bid >> 3);
    const int bm = x / nbn, bn = x % nbn;
    const int m0 = bm * 128, n0 = bn * 128;

    const int NT = K >> 6;                  // 16
    const int NI = NT >> 1;                 // 8

    char* const A0 = sm;
    char* const B0 = sm + 16384;
    char* const A1 = sm + 32768;
    char* const B1 = sm + 49152;

    int offA2[2][4], offB2[2][2];
#pragma unroll
    for (int kk = 0; kk < 2; ++kk) {
#pragma unroll
        for (int m = 0; m < 4; ++m) {
            int rowL = wm * 64 + m * 16 + r;
            offA2[kk][m] = rowL * 128 + (((kk * 4 + hi) ^ (rowL & 7)) * 16);
        }
#pragma unroll
        for (int n = 0; n < 2; ++n) {
            int rowL = wn * 32 + n * 16 + r;
            offB2[kk][n] = rowL * 128 + (((kk * 4 + hi) ^ (rowL & 7)) * 16);
        }
    }

    f32x4 acc[4][2];
#pragma unroll
    for (int am = 0; am < 4; ++am)
#pragma unroll
        for (int an = 0; an < 2; ++an) acc[am][an] = (f32x4){0.f, 0.f, 0.f, 0.f};

    bf16x8 a2[2][2], b2[2][2];

    STAGE_U(A,  K, m0,       0, A0);
    STAGE_U(A,  K, m0 + 64,  0, A0 + 8192);
    STAGE_U(Bt, K, n0,       0, B0);
    STAGE_U(Bt, K, n0 + 64,  0, B0 + 8192);
    STAGE_U(Bt, K, n0,      64, B1);
    STAGE_U(Bt, K, n0 + 64, 64, B1 + 8192);
    asm volatile("s_waitcnt vmcnt(2)" ::: "memory");
    __builtin_amdgcn_s_barrier();

    for (int i = 0; i < NI; ++i) {
        const int k1 = (2 * i + 1) * 64;
        const int k2 = ((2 * i + 2) % NT) * 64;
        const int k3 = ((2 * i + 3) % NT) * 64;

        STAGE_U(A, K, m0,      k1, A1);
        STAGE_U(A, K, m0 + 64, k1, A1 + 8192);
        G2_DSA(A0, 0); G2_DSB(B0);
        BAR_LGKM; G2_MFMA(0);
        __builtin_amdgcn_s_barrier();

        STAGE_U(Bt, K, n0,      k2, B0);
        STAGE_U(Bt, K, n0 + 64, k2, B0 + 8192);
        G2_DSA(A0, 1);
        BAR_LGKM; G2_MFMA(1);
        asm volatile("s_waitcnt vmcnt(2)" ::: "memory");
        __builtin_amdgcn_s_barrier();

        STAGE_U(A, K, m0,      k2, A0);
        STAGE_U(A, K, m0 + 64, k2, A0 + 8192);
        G2_DSA(A1, 0); G2_DSB(B1);
        BAR_LGKM; G2_MFMA(0);
        __builtin_amdgcn_s_barrier();

        STAGE_U(Bt, K, n0,      k3, B1);
        STAGE_U(Bt, K, n0 + 64, k3, B1 + 8192);
        G2_DSA(A1, 1);
        BAR_LGKM; G2_MFMA(1);
        asm volatile("s_waitcnt vmcnt(2)" ::: "memory");
        __builtin_amdgcn_s_barrier();
    }

#pragma unroll
    for (int am = 0; am < 4; ++am) {
        int rowg = m0 + wm * 64 + am * 16 + hi * 4;
#pragma unroll
        for (int an = 0; an < 2; ++an) {
            int colg = n0 + wn * 32 + an * 16 + r;
            float bv = bias[colg];
#pragma unroll
            for (int j = 0; j < 4; ++j)
                Cout[(size_t)(rowg + j) * N + colg] = acc[am][an][j] + bv;
        }
    }
}

// ---------- banded attention v3 (best-measured): 2 barriers, P aliases K,
// V^T staged from vtbuf; 50176B LDS. ----------
__global__ __launch_bounds__(256, 4)
void attn_kernel(const ushort_t* __restrict__ qkv, const ushort_t* __restrict__ vt,
                 ushort_t* __restrict__ attn_out) {
    __shared__ uint4 smem4[50176 / 16];
    char* smem = (char*)smem4;

    const int bid0 = blockIdx.x;
    const int bid = (bid0 & 7) * 128 + (bid0 >> 3);   // XCD-chunked
    const int qb = bid & 31;
    const int h = (bid >> 5) & 15;
    const int b = bid >> 9;
    const int q0 = qb * 64;
    const int kstart = (q0 - 64 > 0) ? (q0 - 64) : 0;

    const int tid = threadIdx.x;
    const int lane = tid & 63;
    const int w = tid >> 6;
    const int r = lane & 15, hi = lane >> 4;

    // ---- stage K [192][64] @0 (swizzled, zero-fill OOB) ----
#pragma unroll
    for (int i = 0; i < 6; ++i) {
        int task = i * 256 + tid;
        int row = task >> 3, ch = task & 7;
        int key = kstart + row;
        uint4 v = make_uint4(0u, 0u, 0u, 0u);
        if (key < SQ)
            v = *reinterpret_cast<const uint4*>(
                qkv + (size_t)(b * SQ + key) * 3072 + 1024 + h * 64 + ch * 8);
        int byte = row * 128 + ch * 16; byte ^= (row & 7) << 4;
        *reinterpret_cast<uint4*>(smem + byte) = v;
    }
    // ---- stage V^T [64 d][192 k] @25600 from vtbuf ----
    {
        const ushort_t* vtb = vt + (size_t)(b * NH + h) * HD * SQ;
        int d = tid >> 2, cp = tid & 3;
#pragma unroll
        for (int i = 0; i < 6; ++i) {
            int c = cp + i * 4;                 // chunk 0..23 (16B each, 8 keys)
            uint4 v = make_uint4(0u, 0u, 0u, 0u);
            int k8 = kstart + c * 8;
            if (k8 < SQ)
                v = *reinterpret_cast<const uint4*>(vtb + (size_t)d * SQ + k8);
            int byte = d * 384 + (((c & 7) ^ (d & 7)) * 16) + ((c >> 3) * 128);
            *reinterpret_cast<uint4*>(smem + 25600 + byte) = v;
        }
    }

    // ---- Q directly into A-fragments ----
    const ushort_t* qrow = qkv + (size_t)(b * SQ + q0 + w * 16 + r) * 3072 + h * 64;
    bf16x8 aq0 = *reinterpret_cast<const bf16x8*>(qrow + hi * 8);
    bf16x8 aq1 = *reinterpret_cast<const bf16x8*>(qrow + 32 + hi * 8);

    __syncthreads();   // barrier #1: staging complete

    const int delta = q0 - kstart;
    const int base = w * 16 + delta;
    int tmin = (base - 64) >> 4; if (tmin < 0) tmin = 0;
    int tmax = (base + 79) >> 4;
    int tcap = (SQ - 1 - kstart) >> 4; if (tmax > tcap) tmax = tcap;
    if (tmax > 11) tmax = 11;
    const int ksmin = tmin >> 1, ksmax = tmax >> 1;

    f32x4 acc[12];
#pragma unroll
    for (int t = 0; t < 12; ++t) acc[t] = (f32x4){0.f, 0.f, 0.f, 0.f};
#pragma unroll
    for (int t = 0; t < 12; ++t) {
        if (t < tmin || t > tmax) continue;
#pragma unroll
        for (int ks = 0; ks < 2; ++ks) {
            int row = t * 16 + r;
            int byte = row * 128 + ks * 64 + hi * 16; byte ^= (row & 7) << 4;
            bf16x8 bk = *reinterpret_cast<const bf16x8*>(smem + byte);
            acc[t] = __builtin_amdgcn_mfma_f32_16x16x32_bf16(
                ks == 0 ? aq0 : aq1, bk, acc[t], 0, 0, 0);
        }
    }

    float mrow[4], lrow[4];
#pragma unroll
    for (int t = 0; t < 12; ++t) {
        if (t < tmin || t > tmax) continue;
        int key = kstart + t * 16 + r;
#pragma unroll
        for (int j = 0; j < 4; ++j) {
            int qrow_g = q0 + w * 16 + hi * 4 + j;
            int dd = key - qrow_g; if (dd < 0) dd = -dd;
            bool valid = (key < SQ) && (dd <= 64);
            acc[t][j] = valid ? acc[t][j] * 0.125f : -1e30f;
        }
    }
#pragma unroll
    for (int j = 0; j < 4; ++j) {
        float m = -1e30f;
#pragma unroll
        for (int t = 0; t < 12; ++t) {
            if (t < tmin || t > tmax) continue;
            m = fmaxf(m, acc[t][j]);
        }
        m = fmaxf(m, __shfl_xor(m, 1));
        m = fmaxf(m, __shfl_xor(m, 2));
        m = fmaxf(m, __shfl_xor(m, 4));
        m = fmaxf(m, __shfl_xor(m, 8));
        mrow[j] = m;
    }
#pragma unroll
    for (int j = 0; j < 4; ++j) {
        float s = 0.f;
#pragma unroll
        for (int t = 0; t < 12; ++t) {
            if (t < tmin || t > tmax) continue;
            float p = __expf(acc[t][j] - mrow[j]);
            acc[t][j] = p;
            s += p;
        }
        s += __shfl_xor(s, 1);
        s += __shfl_xor(s, 2);
        s += __shfl_xor(s, 4);
        s += __shfl_xor(s, 8);
        lrow[j] = s;
    }

    __syncthreads();   // barrier #2: all QK^T reads of K done; P may overwrite

#pragma unroll
    for (int t = 0; t < 12; ++t) {
        int col = t * 16 + r;
        bool inb = (t >= tmin) && (t <= tmax);
#pragma unroll
        for (int j = 0; j < 4; ++j) {
            int rowL = w * 16 + hi * 4 + j;
            ushort_t pv = inb ? f2bf(acc[t][j]) : (ushort_t)0;
            *reinterpret_cast<ushort_t*>(smem + rowL * 400 + col * 2) = pv;
        }
    }
    // same-wave write->read dependency: compiler inserts lgkmcnt; no barrier.

    f32x4 oacc[4];
#pragma unroll
    for (int dt = 0; dt < 4; ++dt) oacc[dt] = (f32x4){0.f, 0.f, 0.f, 0.f};
#pragma unroll
    for (int ks = 0; ks < 6; ++ks) {
        if (ks < ksmin || ks > ksmax) continue;
        int k0 = ks * 32 + hi * 8;
        bf16x8 ap = *reinterpret_cast<const bf16x8*>(
            smem + (w * 16 + r) * 400 + k0 * 2);
        int cch = ks * 4 + hi;                  // 16B chunk index 0..23
#pragma unroll
        for (int dt = 0; dt < 4; ++dt) {
            int d = dt * 16 + r;
            int byte = d * 384 + (((cch & 7) ^ (d & 7)) * 16) + ((cch >> 3) * 128);
            bf16x8 bv = *reinterpret_cast<const bf16x8*>(smem + 25600 + byte);
            oacc[dt] = __builtin_amdgcn_mfma_f32_16x16x32_bf16(ap, bv, oacc[dt], 0, 0, 0);
        }
    }

    float inv[4];
#pragma unroll
    for (int j = 0; j < 4; ++j) inv[j] = 1.0f / lrow[j];
#pragma unroll
    for (int dt = 0; dt < 4; ++dt) {
        int d = dt * 16 + r;
#pragma unroll
        for (int j = 0; j < 4; ++j) {
            int q = q0 + w * 16 + hi * 4 + j;
            attn_out[(size_t)(b * SQ + q) * 1024 + h * 64 + d] = f2bf(oacc[dt][j] * inv[j]);
        }
    }
}

// ---------- launch ----------
extern "C" void kernel_launch(void* const* d_in, const int* in_sizes, int n_in,
                              void* d_out, int out_size, void* d_ws, size_t ws_size,
                              hipStream_t stream) {
    const float* x     = (const float*)d_in[0];
    const float* w_qkv = (const float*)d_in[1];
    const float* b_qkv = (const float*)d_in[2];
    const float* w_out = (const float*)d_in[3];
    const float* b_out = (const float*)d_in[4];
    float* out = (float*)d_out;

    char* ws = (char*)d_ws;
    ushort_t* xb    = (ushort_t*)(ws);                       // 8 MB  [4096][1024]
    ushort_t* wqkvT = (ushort_t*)(ws + 8388608);             // 6 MB  [3072][1024]
    ushort_t* woutT = (ushort_t*)(ws + 14680064);            // 2 MB  [1024][1024]
    ushort_t* qkv   = (ushort_t*)(ws + 16777216);            // 24 MB [4096][3072] (V cols unused)
    ushort_t* aout  = (ushort_t*)(ws + 41943040);            // 8 MB  [4096][1024]
    ushort_t* vtbuf = (ushort_t*)(ws + 50331648);            // 8 MB  [32][64][2048]

    prep_kernel<<<5120, 256, 0, stream>>>(x, xb, w_qkv, wqkvT, w_out, woutT);

    // GEMM1 writes Q/K cols to qkv and V cols transposed into vtbuf directly.
    gemm192_bt<<<256, 512, 0, stream>>>(xb, wqkvT, b_qkv, qkv, vtbuf,
                                        4096, 3072, 1024, 16);
    attn_kernel<<<1024, 256, 0, stream>>>(qkv, vtbuf, aout);
    gemm128_4ph<<<256, 512, 0, stream>>>(aout, woutT, b_out, out, 4096, 1024, 1024, 8);
}